// Round 2
// baseline (239.454 us; speedup 1.0000x reference)
//
#include <hip/hip_runtime.h>

#define Hh 240
#define Ww 304
#define IN_CH 16
#define OUT_CH 32
#define Bb 8
#define N_PER 65536
#define N_EV (Bb * N_PER)      // 524288
#define CIN (IN_CH + 2)        // 18
#define NSEG (Bb * Hh * Ww)    // 583680 = 570 * 1024
#define NBLK 570               // scan blocks of 1024 elems

// fused conv tiling
#define TW 32
#define TH 8
#define HW_ 34                 // TW + 2 halo
#define HH_ 10                 // TH + 2 halo
#define HALO_PIX (HH_ * HW_)   // 340
#define NXT_TILES 10           // ceil(304/32)
#define NYT_TILES 30           // 240/8
#define OPITCH 33              // out repack pitch (f32)

typedef __attribute__((ext_vector_type(8))) short bf16x8;
typedef __attribute__((ext_vector_type(4))) float f32x4;

__device__ __forceinline__ unsigned short f2bf(float x) {
  unsigned u = __float_as_uint(x);
  unsigned r = u + 0x7fffu + ((u >> 16) & 1u);  // RNE
  return (unsigned short)(r >> 16);
}

// ---- A: histogram + rank per event (one atomic pass) -----------------------
__global__ __launch_bounds__(256) void hist_rank_kernel(
    const float* __restrict__ events, const int* __restrict__ offsets,
    int* __restrict__ hist, int* __restrict__ keyArr, int* __restrict__ rankArr) {
  int i = blockIdx.x * blockDim.x + threadIdx.x;
  float4 ev = ((const float4*)events)[i];
  int yi = (int)rintf(ev.y * (float)Hh);
  yi = min(max(yi, 0), Hh - 1);
  int xi = (int)rintf(ev.x * (float)Ww);
  xi = min(max(xi, 0), Ww - 1);
  int b = 0;
#pragma unroll
  for (int j = 0; j < Bb; j++) b += (offsets[j] <= i) ? 1 : 0;
  int key = (b * Hh + yi) * Ww + xi;
  int pol = (ev.w != 0.0f) ? 1 : 0;
  keyArr[i] = key | (pol << 31);
  rankArr[i] = atomicAdd(&hist[key], 1);
}

// ---- S1: per-1024-block exclusive scan + block totals ----------------------
__global__ __launch_bounds__(256) void scan1_kernel(
    const int* __restrict__ hist, int* __restrict__ baseLocal,
    int* __restrict__ blockSum) {
  __shared__ int lds[256];
  int b = blockIdx.x, t = threadIdx.x;
  int idx = b * 1024 + t * 4;
  int4 v = *(const int4*)(hist + idx);
  int s0 = v.x, s1 = s0 + v.y, s2 = s1 + v.z, s3 = s2 + v.w;
  lds[t] = s3;
  __syncthreads();
  int val = s3;
  for (int off = 1; off < 256; off <<= 1) {
    int n = (t >= off) ? lds[t - off] : 0;
    __syncthreads();
    val += n;
    lds[t] = val;
    __syncthreads();
  }
  int excl = val - s3;
  int4 o;
  o.x = excl; o.y = excl + s0; o.z = excl + s1; o.w = excl + s2;
  *(int4*)(baseLocal + idx) = o;
  if (t == 255) blockSum[b] = val;
}

// ---- S2 + W merged: block 0 scans 570 totals; block 1 packs weights --------
__global__ __launch_bounds__(1024) void scan2_weights_kernel(
    const int* __restrict__ blockSum, int* __restrict__ blockOffset,
    const float* __restrict__ weight, unsigned short* __restrict__ wprep) {
  int t = threadIdx.x;
  if (blockIdx.x == 1) {
    // pack weights to [ky][n][64] bf16, zero-padded k>=54
#pragma unroll
    for (int it = 0; it < 6; it++) {
      int idx = it * 1024 + t;              // < 3*32*64 = 6144
      int ky = idx >> 11;
      int rem = idx & 2047;
      int n = rem >> 6;
      int kl = rem & 63;
      unsigned short v = 0;
      if (kl < 54) {
        int kx = kl / 18, ci = kl - kx * 18;
        v = f2bf(weight[((ky * 3 + kx) * CIN + ci) * OUT_CH + n]);
      }
      wprep[idx] = v;
    }
    return;
  }
  __shared__ int lds[1024];
  int v = (t < NBLK) ? blockSum[t] : 0;
  lds[t] = v;
  __syncthreads();
  int val = v;
  for (int off = 1; off < 1024; off <<= 1) {
    int n = (t >= off) ? lds[t - off] : 0;
    __syncthreads();
    val += n;
    lds[t] = val;
    __syncthreads();
  }
  if (t < NBLK) blockOffset[t] = val - v;
  if (t == 0) blockOffset[NBLK] = lds[1023];  // = N_EV
}

// ---- B: scatter ONLY the 4-byte event index into sorted order --------------
__global__ __launch_bounds__(256) void scatter_idx_kernel(
    const int* __restrict__ keyArr, const int* __restrict__ rankArr,
    const int* __restrict__ baseLocal, const int* __restrict__ blockOffset,
    int* __restrict__ sortedMeta) {
  int i = blockIdx.x * blockDim.x + threadIdx.x;
  int meta = keyArr[i];
  int key = meta & 0x7fffffff;
  int pos = baseLocal[key] + blockOffset[key >> 10] + rankArr[i];
  sortedMeta[pos] = i | (meta & 0x80000000);
}

// ---- C: fused conv. Stage 1 is PER-EVENT parallel: flatten the tile's
// events (each halo row is one contiguous sorted range), binary-search the
// owning pixel in LDS, gather features[e] (aligned 64B line), accumulate via
// LDS f32 atomics. Kills the serial per-pixel latency chain of the old code.
__global__ __launch_bounds__(256) void fused_conv_kernel(
    const float* __restrict__ features, const int* __restrict__ sortedMeta,
    const int* __restrict__ baseLocal, const int* __restrict__ blockOffset,
    const unsigned short* __restrict__ wprep, const float* __restrict__ bias,
    float* __restrict__ out) {
  __shared__ float haloAcc[HALO_PIX * CIN];  // 24480B; aliased as out repack
  __shared__ unsigned haloBf[3072];          // bf16 halo, 12288B
  __shared__ int pixBase[HALO_PIX];          // sentinel-laden for search
  __shared__ int pixCnt[HALO_PIX];
  __shared__ int rowStart[HH_];
  __shared__ int rowPfx[HH_ + 1];

  int blk = blockIdx.x;
  int xt = blk % NXT_TILES;
  int rem = blk / NXT_TILES;
  int yt = rem % NYT_TILES;
  int b = rem / NYT_TILES;
  int x0 = xt * TW, y0 = yt * TH;
  int tid = threadIdx.x;

  if (tid < 12) haloBf[3060 + tid] = 0;  // zero A-read overrun pad

  // ---- stage 1a: per-pixel setup (base, count), zero accumulators ----
  for (int h = tid; h < HALO_PIX; h += 256) {
    int hy = h / HW_, hx = h % HW_;
    int gy = y0 - 1 + hy, gx = x0 - 1 + hx;
    int base = 0, c = 0;
    bool valid = (gy >= 0 && gy < Hh && gx >= 0 && gx < Ww);
    if (valid) {
      int p = (b * Hh + gy) * Ww + gx;
      int bo = blockOffset[p >> 10];
      base = baseLocal[p] + bo;
      int nxt = ((p & 1023) != 1023) ? (baseLocal[p + 1] + bo)
                                     : blockOffset[(p >> 10) + 1];
      c = nxt - base;
    }
    // sentinels keep the per-row base array monotone for the search:
    // left-invalid -> 0 (never rightmost), right-invalid -> +inf (never <= q)
    pixBase[h] = valid ? base : (gx < 0 ? 0 : 0x7fffffff);
    pixCnt[h] = c;
#pragma unroll
    for (int k = 0; k < CIN; k++) haloAcc[h * CIN + k] = 0.0f;
  }
  __syncthreads();

  // ---- stage 1b: per-row contiguous ranges ----
  if (tid < HH_) {
    int s = 0;
#pragma unroll
    for (int x = 0; x < HW_; x++) s += pixCnt[tid * HW_ + x];
    rowPfx[tid + 1] = s;
    rowStart[tid] = pixBase[tid * HW_ + ((x0 == 0) ? 1 : 0)];
  }
  if (tid == 0) rowPfx[0] = 0;
  __syncthreads();
  if (tid == 0) {
#pragma unroll
    for (int r = 1; r <= HH_; r++) rowPfx[r] += rowPfx[r - 1];
  }
  __syncthreads();
  int T = rowPfx[HH_];

  // ---- stage 1c: per-event parallel gather + LDS atomic accumulate ----
  for (int t = tid; t < T; t += 256) {
    int r = 0;
    while (r < HH_ - 1 && rowPfx[r + 1] <= t) ++r;
    int q = rowStart[r] + (t - rowPfx[r]);
    // rightmost pixel in row r with base <= q  (== owner of position q)
    int lo = r * HW_, hi = lo + HW_ - 1;
    while (lo < hi) {
      int mid = (lo + hi + 1) >> 1;
      if (pixBase[mid] <= q) lo = mid; else hi = mid - 1;
    }
    int meta = sortedMeta[q];  // mostly coalesced (consecutive t -> q)
    float pol = (float)((unsigned)meta >> 31);
    int e = meta & 0x7fffffff;
    const float4* f = (const float4*)(features + (size_t)e * IN_CH);
    float4 f0 = f[0], f1 = f[1], f2 = f[2], f3 = f[3];
    float* hA = haloAcc + lo * CIN;
    atomicAdd(hA + 0, pol);
    atomicAdd(hA + 1, 1.0f - pol);
    atomicAdd(hA + 2, f0.x);  atomicAdd(hA + 3, f0.y);
    atomicAdd(hA + 4, f0.z);  atomicAdd(hA + 5, f0.w);
    atomicAdd(hA + 6, f1.x);  atomicAdd(hA + 7, f1.y);
    atomicAdd(hA + 8, f1.z);  atomicAdd(hA + 9, f1.w);
    atomicAdd(hA + 10, f2.x); atomicAdd(hA + 11, f2.y);
    atomicAdd(hA + 12, f2.z); atomicAdd(hA + 13, f2.w);
    atomicAdd(hA + 14, f3.x); atomicAdd(hA + 15, f3.y);
    atomicAdd(hA + 16, f3.z); atomicAdd(hA + 17, f3.w);
  }
  __syncthreads();

  // ---- stage 1d: normalize + pack bf16 halo ----
  for (int h = tid; h < HALO_PIX; h += 256) {
    float inv = 1.0f / fmaxf((float)pixCnt[h], 1.0f);
    unsigned* row = haloBf + 9 * h;  // 18 bf16 = 9 dwords
#pragma unroll
    for (int k = 0; k < 9; k++)
      row[k] = (unsigned)f2bf(haloAcc[h * CIN + 2 * k] * inv) |
               ((unsigned)f2bf(haloAcc[h * CIN + 2 * k + 1] * inv) << 16);
  }
  __syncthreads();

  // ---- stage 2: MFMA GEMM from LDS halo (ky-outer to cut VGPR) ----
  int wv = tid >> 6, lane = tid & 63;
  int quad = lane >> 4, lrow = lane & 15;

  f32x4 accf[4][2];
#pragma unroll
  for (int i = 0; i < 4; i++)
#pragma unroll
    for (int nt = 0; nt < 2; nt++) accf[i][nt] = (f32x4){0.f, 0.f, 0.f, 0.f};

  const unsigned* hp = haloBf;
#pragma unroll
  for (int ky = 0; ky < 3; ky++) {
    bf16x8 bfr[2][2];  // [khalf][ntile]
#pragma unroll
    for (int kh = 0; kh < 2; kh++)
#pragma unroll
      for (int nt = 0; nt < 2; nt++) {
        int n = nt * 16 + lrow;
        bfr[kh][nt] = *(const bf16x8*)(wprep + ((ky * 32 + n) << 6) +
                                       kh * 32 + quad * 8);
      }
#pragma unroll
    for (int i = 0; i < 4; i++) {  // m-tiles of this wave
      int t0 = (wv * 4 + i) * 16;
      int ox = (t0 & 31) + lrow;   // A: m = lane&15
      int oy = t0 >> 5;
      int idx0 = ((oy + ky) * HW_ + ox) * CIN;  // even (shorts)
#pragma unroll
      for (int kh = 0; kh < 2; kh++) {
        union { bf16x8 v; unsigned u[4]; } a;
        int ui = (idx0 >> 1) + kh * 16 + quad * 4;
        a.u[0] = hp[ui]; a.u[1] = hp[ui + 1];
        a.u[2] = hp[ui + 2]; a.u[3] = hp[ui + 3];
        accf[i][0] = __builtin_amdgcn_mfma_f32_16x16x32_bf16(
            a.v, bfr[kh][0], accf[i][0], 0, 0, 0);
        accf[i][1] = __builtin_amdgcn_mfma_f32_16x16x32_bf16(
            a.v, bfr[kh][1], accf[i][1], 0, 0, 0);
      }
    }
  }
  __syncthreads();  // haloAcc dead; reuse as out repack (128 rows x 33)

  // ---- stages 3+4, chunked (2 x 32 pixels per wave) to halve LDS ----
  float* outsh = haloAcc;
  float bn0 = bias[lrow], bn1 = bias[16 + lrow];  // D: col = lane&15
  int gx = x0 + (tid & 31);
  int hint = ((tid >> 5) + 1) * HW_ + (tid & 31) + 1;  // interior pixel
  int c = pixCnt[hint];
  int base = pixBase[hint];
#pragma unroll
  for (int ch = 0; ch < 2; ch++) {
#pragma unroll
    for (int ii = 0; ii < 2; ii++) {
      int i = ch * 2 + ii;
      int lidx = ii * 16 + quad * 4;         // local row within chunk [0,32)
      int row = wv * 32 + lidx;
#pragma unroll
      for (int r = 0; r < 4; r++) {
        outsh[(row + r) * OPITCH + lrow] = accf[i][0][r] + bn0;
        outsh[(row + r) * OPITCH + 16 + lrow] = accf[i][1][r] + bn1;
      }
    }
    __syncthreads();
    if (((tid >> 5) & 1) == ch && gx < Ww && c > 0) {
      int row = (tid >> 6) * 32 + ((tid & 63) - ch * 32);
      const float* rp = outsh + row * OPITCH;
      float4 o0 = make_float4(rp[0], rp[1], rp[2], rp[3]);
      float4 o1 = make_float4(rp[4], rp[5], rp[6], rp[7]);
      float4 o2 = make_float4(rp[8], rp[9], rp[10], rp[11]);
      float4 o3 = make_float4(rp[12], rp[13], rp[14], rp[15]);
      float4 o4 = make_float4(rp[16], rp[17], rp[18], rp[19]);
      float4 o5 = make_float4(rp[20], rp[21], rp[22], rp[23]);
      float4 o6 = make_float4(rp[24], rp[25], rp[26], rp[27]);
      float4 o7 = make_float4(rp[28], rp[29], rp[30], rp[31]);
      for (int j = 0; j < c; j++) {
        int ev = sortedMeta[base + j] & 0x7fffffff;
        float4* op = (float4*)(out + (size_t)ev * OUT_CH);
        op[0] = o0; op[1] = o1; op[2] = o2; op[3] = o3;
        op[4] = o4; op[5] = o5; op[6] = o6; op[7] = o7;
      }
    }
    __syncthreads();
  }
}

extern "C" void kernel_launch(void* const* d_in, const int* in_sizes, int n_in,
                              void* d_out, int out_size, void* d_ws,
                              size_t ws_size, hipStream_t stream) {
  const float* events = (const float*)d_in[0];
  const float* features = (const float*)d_in[1];
  const float* weight = (const float*)d_in[2];
  const float* bias = (const float*)d_in[3];
  const int* offsets = (const int*)d_in[4];
  float* out = (float*)d_out;

  int* sortedMeta = (int*)d_ws;                       // N_EV
  int* keyArr = sortedMeta + N_EV;                    // N_EV
  int* rankArr = keyArr + N_EV;                       // N_EV
  int* hist = rankArr + N_EV;                         // NSEG
  int* baseLocal = hist + NSEG;                       // NSEG
  int* blockOffset = baseLocal + NSEG;                // NBLK+1 (pad 1024)
  int* blockSum = blockOffset + 1024;                 // NBLK (pad 1024)
  unsigned short* wprep = (unsigned short*)(blockSum + 1024);  // 6144 ushort

  hipMemsetAsync(hist, 0, (size_t)NSEG * sizeof(int), stream);

  hist_rank_kernel<<<N_EV / 256, 256, 0, stream>>>(events, offsets, hist,
                                                   keyArr, rankArr);
  scan1_kernel<<<NBLK, 256, 0, stream>>>(hist, baseLocal, blockSum);
  scan2_weights_kernel<<<2, 1024, 0, stream>>>(blockSum, blockOffset, weight,
                                               wprep);
  scatter_idx_kernel<<<N_EV / 256, 256, 0, stream>>>(
      keyArr, rankArr, baseLocal, blockOffset, sortedMeta);
  fused_conv_kernel<<<Bb * NYT_TILES * NXT_TILES, 256, 0, stream>>>(
      features, sortedMeta, baseLocal, blockOffset, wprep, bias, out);
}